// Round 11
// baseline (535.877 us; speedup 1.0000x reference)
//
#include <hip/hip_runtime.h>

#define NB 64
#define NT 4096
#define CH 8
#define KC (NT/CH)        // 512 chunks per batch
#define GPB 16            // 16-lane groups per 256-thread block
#define NA 128            // spectral-norm table size over [0, pi)
#define NM 14             // hoisted G-power basis matrices
#define QTR 72            // padded tr-block stride (72 mod 32 = 8 -> 2-way max)
#define QMS (4*QTR)       // 288 floats per padded Q matrix
#define PI_F 3.14159265358979f

#define C3c (1.f/6.f)
#define C4c (1.f/24.f)
#define C5c (1.f/120.f)
#define C6c (1.f/720.f)
#define C7c (1.f/5040.f)
#define C8c (1.f/40320.f)

typedef float v2f __attribute__((ext_vector_type(2)));

// ---------------- packed register-resident 16x16 matmul (k1) ----------------
// Lane u = 4*tr+tc holds tile X[4tr+rr][4tc+cc]; packed: x[rr*2+h] = cols
// (2h, 2h+1).  acc += A@B over k-block K:
//   A-slice: quad-mate K via DPP quad_perm[K,K,K,K] (scalar).
//   B-slice: lane (K,tc) via ds_swizzle BitMode src=(lane&0x13)|(K<<2).
//   FMA: v_pk_fma_f32 via __builtin_elementwise_fma on float2.
template<int K>
__device__ __forceinline__ void mm_step(v2f acc[8], const v2f a[8], const v2f b[8]) {
  v2f bb[8];
#pragma unroll
  for (int e = 0; e < 8; ++e) {
    bb[e].x = __int_as_float(__builtin_amdgcn_ds_swizzle(__float_as_int(b[e].x), (K << 7) | 0x13));
    bb[e].y = __int_as_float(__builtin_amdgcn_ds_swizzle(__float_as_int(b[e].y), (K << 7) | 0x13));
  }
#pragma unroll
  for (int rr = 0; rr < 4; ++rr) {
#pragma unroll
    for (int c = 0; c < 4; ++c) {
      const v2f pa = a[rr*2 + (c >> 1)];
      const float as = (c & 1) ? pa.y : pa.x;
      const float ab = __int_as_float(__builtin_amdgcn_mov_dpp(__float_as_int(as), K*0x55, 0xF, 0xF, true));
      const v2f av = {ab, ab};
      acc[rr*2+0] = __builtin_elementwise_fma(av, bb[c*2+0], acc[rr*2+0]);
      acc[rr*2+1] = __builtin_elementwise_fma(av, bb[c*2+1], acc[rr*2+1]);
    }
  }
}
__device__ __forceinline__ void mmreg(v2f acc[8], const v2f a[8], const v2f b[8]) {
  mm_step<0>(acc, a, b); mm_step<1>(acc, a, b);
  mm_step<2>(acc, a, b); mm_step<3>(acc, a, b);
}

// ---------------- k0: rho table + hoisted G-power basis ----------------
__global__ __launch_bounds__(256) void k0_prep(const float* __restrict__ A1,
                                               const float* __restrict__ A2,
                                               float* __restrict__ ws) {
  __shared__ float S[2][256], W2[4][256], W3[8][256], W4[16][256];
  const int tid = threadIdx.x;
  {
    int i_ = tid >> 4, j_ = tid & 15;
    S[0][tid] = A1[i_*16+j_] - A1[j_*16+i_];
    S[1][tid] = A2[i_*16+j_] - A2[j_*16+i_];
  }
  __syncthreads();
  const int i = tid >> 4, j = tid & 15;
#pragma unroll
  for (int p = 0; p < 4; ++p) {
    const float* a = S[p>>1]; const float* bm = S[p&1];
    float acc = 0.f;
    for (int k = 0; k < 16; ++k) acc = fmaf(a[i*16+k], bm[k*16+j], acc);
    W2[p][tid] = acc;
  }
  __syncthreads();
#pragma unroll
  for (int p = 0; p < 8; ++p) {
    const float* a = S[p>>2]; const float* bm = W2[p&3];
    float acc = 0.f;
    for (int k = 0; k < 16; ++k) acc = fmaf(a[i*16+k], bm[k*16+j], acc);
    W3[p][tid] = acc;
  }
  __syncthreads();
#pragma unroll
  for (int p = 0; p < 16; ++p) {
    const float* a = S[p>>3]; const float* bm = W3[p&7];
    float acc = 0.f;
    for (int k = 0; k < 16; ++k) acc = fmaf(a[i*16+k], bm[k*16+j], acc);
    W4[p][tid] = acc;
  }
  __syncthreads();
  float* M = ws + NA;
  M[ 0*256+tid] = S[0][tid];
  M[ 1*256+tid] = S[1][tid];
  M[ 2*256+tid] = W2[0][tid];
  M[ 3*256+tid] = W2[1][tid] + W2[2][tid];
  M[ 4*256+tid] = W2[3][tid];
  M[ 5*256+tid] = W3[0][tid];
  M[ 6*256+tid] = W3[1][tid] + W3[2][tid] + W3[4][tid];
  M[ 7*256+tid] = W3[3][tid] + W3[5][tid] + W3[6][tid];
  M[ 8*256+tid] = W3[7][tid];
  M[ 9*256+tid] = W4[0][tid];
  M[10*256+tid] = W4[1][tid] + W4[2][tid] + W4[4][tid] + W4[8][tid];
  M[11*256+tid] = W4[3][tid] + W4[5][tid] + W4[6][tid] + W4[9][tid] + W4[10][tid] + W4[12][tid];
  M[12*256+tid] = W4[7][tid] + W4[11][tid] + W4[13][tid] + W4[14][tid];
  M[13*256+tid] = W4[15][tid];
  if (tid < NA) {
    const float th = (float)tid * (PI_F / NA);
    const float c = cosf(th), s = sinf(th);
    float v[16];
    float n2 = 0.f;
#pragma unroll
    for (int jj = 0; jj < 16; ++jj) { v[jj] = sinf(1.7f*(float)(jj+1) + th) + 0.25f; n2 += v[jj]*v[jj]; }
    float inv = rsqrtf(n2);
#pragma unroll
    for (int jj = 0; jj < 16; ++jj) v[jj] *= inv;
    float lam = 0.f;
    for (int it = 0; it < 14; ++it) {
      float w[16];
#pragma unroll
      for (int ii = 0; ii < 16; ++ii) {
        float a1 = 0.f, a2 = 0.f;
#pragma unroll
        for (int jj = 0; jj < 16; ++jj) { a1 = fmaf(S[0][ii*16+jj], v[jj], a1); a2 = fmaf(S[1][ii*16+jj], v[jj], a2); }
        w[ii] = c*a1 + s*a2;
      }
      n2 = 0.f;
#pragma unroll
      for (int ii = 0; ii < 16; ++ii) n2 += w[ii]*w[ii];
      lam = sqrtf(n2);
      inv = (lam > 1e-20f) ? 1.f/lam : 0.f;
#pragma unroll
      for (int ii = 0; ii < 16; ++ii) v[ii] = w[ii]*inv;
    }
    ws[tid] = lam * 1.05f;
  }
}

// ---------------- k1: per-chunk scan, packed register mms ----------------
// Qs padded: element (m, row i, col j) at m*QMS + (i>>2)*QTR + (i&3)*16 + j.
__global__ __launch_bounds__(256, 2) void k1_chunk(const float* __restrict__ Z,
                                                   const float* __restrict__ wsrc,
                                                   float* __restrict__ Aout)
{
  __shared__ float Qs[NM*QMS];
  __shared__ float rhos[NA];
  const int tid = threadIdx.x;
  for (int e = tid; e < NM*256; e += 256) {
    const int m = e >> 8, i = (e >> 4) & 15, j = e & 15;
    Qs[m*QMS + (i>>2)*QTR + (i&3)*16 + j] = wsrc[NA + e];
  }
  if (tid < NA) rhos[tid] = wsrc[tid];
  __syncthreads();

  const int g  = tid >> 4;
  const int u  = tid & 15;
  const int tr = u >> 2;
  const int tc = u & 3;
  const int gw = (tid & 63) >> 4;
  const int qbase = tr*QTR + tc*4;

  const int cid    = blockIdx.x * GPB + g;
  const int b      = cid >> 9;          // / KC (KC=512)
  const int kchunk = cid & (KC-1);
  const int t0     = kchunk * CH;

  const float trtc = (tr == tc) ? 1.f : 0.f;
  const int tz = t0 + u;
  float2 za = *(const float2*)&Z[(size_t)(b*NT + (tz < NT ? tz : NT-1)) * 2];

  v2f lt[8];
#pragma unroll
  for (int e = 0; e < 8; ++e) lt[e] = (v2f){0.f, 0.f};
#pragma unroll
  for (int rr = 0; rr < 4; ++rr) {
    if (rr & 1) lt[rr*2 + (rr>>1)].y = trtc;
    else        lt[rr*2 + (rr>>1)].x = trtc;
  }

  const int fstep = (kchunk == 0) ? 1 : 0;

  for (int tt = 0; tt < CH; ++tt) {
    const size_t obase = (size_t)(b*NT + t0 + tt) * 256 + (size_t)(tr*64) + 4*tc;

    const int src = (gw << 4) + tt;
    float z1 = __shfl(za.x, src);
    float z2 = __shfl(za.y, src);
    float r_ = sqrtf(z1*z1 + z2*z2);
    float th = atan2f(z2, z1);
    if (th < 0.f) th += PI_F;
    int idx = ((int)(th * ((float)NA / PI_F) + 0.5f)) & (NA - 1);
    float nrm = r_ * rhos[idx];
    nrm = fmaxf(nrm, __shfl_xor(nrm, 16));
    nrm = fmaxf(nrm, __shfl_xor(nrm, 32));     // wave-uniform
    int s = 0;
    if (nrm > 1.0f) s = (int)ceilf(log2f(nrm));
    const float scl = exp2f(-(float)s);

    if (kchunk == 0 && tt == 0) {
#pragma unroll
      for (int rr = 0; rr < 4; ++rr)
        *(float4*)&Aout[obase + rr*16] =
          make_float4(lt[rr*2].x, lt[rr*2].y, lt[rr*2+1].x, lt[rr*2+1].y);
      continue;
    }

    const float x = z1*scl, y = z2*scl;
    const float x2 = x*x, xy = x*y, y2 = y*y;
    const float x3 = x2*x, x2y = x2*y, xy2 = x*y2, y3 = y2*y;
    const float zc[NM] = { x, y, x2, xy, y2, x3, x2y, xy2, y3,
                           x2*x2, x3*y, x2*y2, x*y3, y2*y2 };
    const float WP[NM] = { 1.f,1.f, .5f,.5f,.5f, C3c,C3c,C3c,C3c, 0.f,0.f,0.f,0.f,0.f };
    const float WU[NM] = { C5c,C5c, C6c,C6c,C6c, C7c,C7c,C7c,C7c, C8c,C8c,C8c,C8c,C8c };

    v2f pp[8], uu[8], g4[8];
#pragma unroll
    for (int e = 0; e < 8; ++e) {
      pp[e] = (v2f){0.f, 0.f}; uu[e] = (v2f){0.f, 0.f}; g4[e] = (v2f){0.f, 0.f};
    }
#pragma unroll
    for (int rr = 0; rr < 4; ++rr) {
      const int h = rr >> 1;
      if (rr & 1) { pp[rr*2+h].y = trtc; uu[rr*2+h].y = trtc * C4c; }
      else        { pp[rr*2+h].x = trtc; uu[rr*2+h].x = trtc * C4c; }
    }
    // P1 = I + G + G2/2 + G3/6 ; U = I/24 + ... + G4/40320 ; G4 separate
#pragma unroll
    for (int m = 0; m < NM; ++m) {
      const float am = zc[m] * WP[m];
      const float bm = zc[m] * WU[m];
      const v2f vam = {am, am}, vbm = {bm, bm}, vzm = {zc[m], zc[m]};
#pragma unroll
      for (int rr = 0; rr < 4; ++rr) {
        float4 v = *(const float4*)&Qs[m*QMS + rr*16 + qbase];
        const v2f q0 = {v.x, v.y}, q1 = {v.z, v.w};
        if (m < 9) {
          pp[rr*2+0] = __builtin_elementwise_fma(vam, q0, pp[rr*2+0]);
          pp[rr*2+1] = __builtin_elementwise_fma(vam, q1, pp[rr*2+1]);
        } else {
          g4[rr*2+0] = __builtin_elementwise_fma(vzm, q0, g4[rr*2+0]);
          g4[rr*2+1] = __builtin_elementwise_fma(vzm, q1, g4[rr*2+1]);
        }
        uu[rr*2+0] = __builtin_elementwise_fma(vbm, q0, uu[rr*2+0]);
        uu[rr*2+1] = __builtin_elementwise_fma(vbm, q1, uu[rr*2+1]);
      }
    }

    mmreg(pp, g4, uu);                         // E = P1 + G4*U

    for (int q = 0; q < s; ++q) {              // wave-uniform squarings
      v2f acc[8];
#pragma unroll
      for (int e = 0; e < 8; ++e) acc[e] = (v2f){0.f, 0.f};
      mmreg(acc, pp, pp);
#pragma unroll
      for (int e = 0; e < 8; ++e) pp[e] = acc[e];
    }
    if (tt == fstep) {                         // L was I: copy
#pragma unroll
      for (int e = 0; e < 8; ++e) lt[e] = pp[e];
    } else {
      v2f acc[8];
#pragma unroll
      for (int e = 0; e < 8; ++e) acc[e] = (v2f){0.f, 0.f};
      mmreg(acc, lt, pp);                      // Lnew = L @ E
#pragma unroll
      for (int e = 0; e < 8; ++e) lt[e] = acc[e];
    }
#pragma unroll
    for (int rr = 0; rr < 4; ++rr)
      *(float4*)&Aout[obase + rr*16] =
        make_float4(lt[rr*2].x, lt[rr*2].y, lt[rr*2+1].x, lt[rr*2+1].y);
  }
}

// ---------------- carry tree + fixup ----------------
// Stash in Binv (per batch): partial carries at t=k*8 (k=0..511),
// subgroup totals at t=128*sb+1, supercarries at t=128*sb+2 (sb=0..31).
#define ROWB 72
#define MATS (4*ROWB)
#define LGS (2*MATS + 8)
#define BX 0
#define BY MATS
#define WSYNC() asm volatile("s_waitcnt lgkmcnt(0)" ::: "memory")

#define MM_FMA(A_, B0_, B1_, B2_, B3_, base) \
  acc[base+0] = fmaf(A_.w, B3_.x, fmaf(A_.z, B2_.x, fmaf(A_.y, B1_.x, fmaf(A_.x, B0_.x, acc[base+0])))); \
  acc[base+1] = fmaf(A_.w, B3_.y, fmaf(A_.z, B2_.y, fmaf(A_.y, B1_.y, fmaf(A_.x, B0_.y, acc[base+1])))); \
  acc[base+2] = fmaf(A_.w, B3_.z, fmaf(A_.z, B2_.z, fmaf(A_.y, B1_.z, fmaf(A_.x, B0_.z, acc[base+2])))); \
  acc[base+3] = fmaf(A_.w, B3_.w, fmaf(A_.z, B2_.w, fmaf(A_.y, B1_.w, fmaf(A_.x, B0_.w, acc[base+3]))));

template<bool CLR>
__device__ __forceinline__ void mmg(float acc[16], const float* sb, int offA, int offB,
                                    const int xA[4], const int xB[4], int trR) {
  if (CLR) {
#pragma unroll
    for (int e = 0; e < 16; ++e) acc[e] = 0.f;
  }
#pragma unroll
  for (int kk = 0; kk < 4; ++kk) {
    const float* pa = sb + offA + trR + xA[kk];
    const float* pb = sb + offB + kk*ROWB + xB[kk];
    float4 a0 = *(const float4*)(pa +  0);
    float4 a1 = *(const float4*)(pa + 16);
    float4 a2 = *(const float4*)(pa + 32);
    float4 a3 = *(const float4*)(pa + 48);
    float4 b0 = *(const float4*)(pb +  0);
    float4 b1 = *(const float4*)(pb + 16);
    float4 b2 = *(const float4*)(pb + 32);
    float4 b3 = *(const float4*)(pb + 48);
    MM_FMA(a0, b0, b1, b2, b3, 0)
    MM_FMA(a1, b0, b1, b2, b3, 4)
    MM_FMA(a2, b0, b1, b2, b3, 8)
    MM_FMA(a3, b0, b1, b2, b3, 12)
  }
}

__device__ __forceinline__ void st4(float* sb, int offD, const float v[16], int trR, int xD) {
  float* p = sb + offD + trR + xD;
#pragma unroll
  for (int rr = 0; rr < 4; ++rr)
    *(float4*)(p + rr*16) = make_float4(v[rr*4+0], v[rr*4+1], v[rr*4+2], v[rr*4+3]);
}

__global__ __launch_bounds__(256) void k2a(const float* __restrict__ Aout,
                                           float* __restrict__ Binv) {
  __shared__ float Cy[256], Lt[256];
  const int tid = threadIdx.x, i = tid >> 4, j = tid & 15;
  const int b = blockIdx.x >> 5, sb = blockIdx.x & 31;
  Cy[tid] = (i == j) ? 1.f : 0.f;
  float nxt = Aout[((size_t)(b*NT + (sb*16)*CH + CH - 1))*256 + tid];
  __syncthreads();
  for (int q = 0; q < 16; ++q) {
    const int k = sb*16 + q;
    Binv[((size_t)(b*NT + k*CH))*256 + tid] = Cy[tid];
    Lt[tid] = nxt;
    __syncthreads();
    if (q < 15) nxt = Aout[((size_t)(b*NT + (k+1)*CH + CH - 1))*256 + tid];
    float a2 = 0.f;
#pragma unroll
    for (int m = 0; m < 16; ++m) a2 = fmaf(Cy[i*16+m], Lt[m*16+j], a2);
    __syncthreads();
    Cy[tid] = a2;
    __syncthreads();
  }
  Binv[((size_t)(b*NT + sb*128 + 1))*256 + tid] = Cy[tid];
}

__global__ __launch_bounds__(256) void k2b(float* __restrict__ Binv) {
  __shared__ float Cy[256], Lt[256];
  const int tid = threadIdx.x, i = tid >> 4, j = tid & 15;
  const int b = blockIdx.x;
  Cy[tid] = (i == j) ? 1.f : 0.f;
  float nxt = Binv[((size_t)(b*NT + 1))*256 + tid];
  __syncthreads();
  for (int sb2 = 0; sb2 < 32; ++sb2) {
    Binv[((size_t)(b*NT + sb2*128 + 2))*256 + tid] = Cy[tid];
    Lt[tid] = nxt;
    __syncthreads();
    if (sb2 < 31) nxt = Binv[((size_t)(b*NT + (sb2+1)*128 + 1))*256 + tid];
    float a2 = 0.f;
#pragma unroll
    for (int m = 0; m < 16; ++m) a2 = fmaf(Cy[i*16+m], Lt[m*16+j], a2);
    __syncthreads();
    Cy[tid] = a2;
    __syncthreads();
  }
}

// k3: staged-LDS mm (proven) + ds_bpermute in-register transpose (round-9
// verified mapping) -> one LDS round-trip per tile instead of two.
__global__ __launch_bounds__(256, 2) void k3_apply(float* __restrict__ Aout,
                                                   float* __restrict__ Binv)
{
  __shared__ __align__(16) float lds[GPB * LGS];
  __shared__ float SupL[256];
  const int tid = threadIdx.x;
  const int g   = tid >> 4;
  const int u   = tid & 15;
  const int tr  = u >> 2;
  const int tc  = u & 3;
  const int gw  = (tid & 63) >> 4;
  const int trR = tr * ROWB;
  float* sb_ = lds + g * LGS;
  const int xA[4] = { ((0^tr)<<2), ((1^tr)<<2), ((2^tr)<<2), ((3^tr)<<2) };
  const int xB[4] = { ((tc^0)<<2), ((tc^1)<<2), ((tc^2)<<2), ((tc^3)<<2) };
  const int xD    = ((tc^tr)<<2);

  const int b   = blockIdx.x >> 5;
  const int sbq = blockIdx.x & 31;
  const int k   = sbq*16 + g;
  const int t0  = k * CH;

  SupL[tid] = Binv[((size_t)(b*NT + sbq*128 + 2))*256 + tid];
  {
    const float* srcp = &Binv[((size_t)(b*NT + k*CH))*256];
#pragma unroll
    for (int rr = 0; rr < 4; ++rr) {
      float4 v = *(const float4*)&srcp[rr*64 + 4*u];
      *(float4*)&sb_[BX + rr*ROWB + tr*16 + ((tc^rr)<<2)] = v;
    }
  }
  __syncthreads();

  float wt[16];
  {
    float* acc = wt;
#pragma unroll
    for (int e = 0; e < 16; ++e) acc[e] = 0.f;
#pragma unroll
    for (int kk = 0; kk < 4; ++kk) {
      const float* pb = sb_ + BX + kk*ROWB + xB[kk];
      float4 b0 = *(const float4*)(pb +  0);
      float4 b1 = *(const float4*)(pb + 16);
      float4 b2 = *(const float4*)(pb + 32);
      float4 b3 = *(const float4*)(pb + 48);
      float4 a0 = *(const float4*)&SupL[(4*tr+0)*16 + 4*kk];
      float4 a1 = *(const float4*)&SupL[(4*tr+1)*16 + 4*kk];
      float4 a2 = *(const float4*)&SupL[(4*tr+2)*16 + 4*kk];
      float4 a3 = *(const float4*)&SupL[(4*tr+3)*16 + 4*kk];
      MM_FMA(a0, b0, b1, b2, b3, 0)
      MM_FMA(a1, b0, b1, b2, b3, 4)
      MM_FMA(a2, b0, b1, b2, b3, 8)
      MM_FMA(a3, b0, b1, b2, b3, 12)
    }
  }
  st4(sb_, BY, wt, trR, xD);   // BY := W for the whole loop
  WSYNC();

  const int bidx = ((gw << 4) + tc*4 + tr) * 4;   // transpose mate (wave-local)
  float acc[16], tp[16];
  for (int tt = 0; tt < CH; ++tt) {
    const size_t base = ((size_t)(b*NT + t0 + tt))*256;
#pragma unroll
    for (int rr = 0; rr < 4; ++rr) {
      float4 v = *(const float4*)&Aout[base + rr*64 + 4*u];
      *(float4*)&sb_[BX + rr*ROWB + tr*16 + ((tc^rr)<<2)] = v;
    }
    WSYNC();
    mmg<true>(acc, sb_, BY, BX, xA, xB, trR);         // A = W @ L
    const size_t obase = base + (size_t)(tr*64) + 4*tc;
#pragma unroll
    for (int rr = 0; rr < 4; ++rr)
      *(float4*)&Aout[obase + rr*16] =
        make_float4(acc[rr*4+0], acc[rr*4+1], acc[rr*4+2], acc[rr*4+3]);
#pragma unroll
    for (int e = 0; e < 16; ++e)
      tp[e] = __int_as_float(__builtin_amdgcn_ds_bpermute(bidx, __float_as_int(acc[e])));
#pragma unroll
    for (int rr = 0; rr < 4; ++rr)
      *(float4*)&Binv[obase + rr*16] =
        make_float4(tp[rr], tp[4+rr], tp[8+rr], tp[12+rr]);   // A^T tile
    WSYNC();   // drain ds reads before next iteration overwrites BX
  }
}

extern "C" void kernel_launch(void* const* d_in, const int* in_sizes, int n_in,
                              void* d_out, int out_size, void* d_ws, size_t ws_size,
                              hipStream_t stream) {
  const float* Z  = (const float*)d_in[0];
  const float* A1 = (const float*)d_in[1];
  const float* A2 = (const float*)d_in[2];
  float* ws   = (float*)d_ws;
  float* Aout = (float*)d_out;
  float* Binv = Aout + (size_t)NB * NT * 256;

  k0_prep<<<1, 256, 0, stream>>>(A1, A2, ws);
  k1_chunk<<<NB * KC / GPB, 256, 0, stream>>>(Z, ws, Aout);
  k2a<<<NB * 32, 256, 0, stream>>>(Aout, Binv);
  k2b<<<NB, 256, 0, stream>>>(Binv);
  k3_apply<<<NB * 32, 256, 0, stream>>>(Aout, Binv);
}

// Round 13
// 526.696 us; speedup vs baseline: 1.0174x; 1.0174x over previous
//
#include <hip/hip_runtime.h>

#define NB 64
#define NT 4096
#define CH 8
#define KC (NT/CH)        // 512 chunks per batch
#define GPB 16            // 16-lane groups per 256-thread block
#define NA 128            // spectral-norm table size over [0, pi)
#define NM 14             // hoisted G-power basis matrices
#define QTR 72            // padded tr-block stride (72 mod 32 = 8 -> 2-way max)
#define QMS (4*QTR)       // 288 floats per padded Q matrix
#define PI_F 3.14159265358979f

#define C3c (1.f/6.f)
#define C4c (1.f/24.f)
#define C5c (1.f/120.f)
#define C6c (1.f/720.f)
#define C7c (1.f/5040.f)
#define C8c (1.f/40320.f)

// ---------------- register-resident 16x16 matmul (k1 only) ----------------
// Lane u = 4*tr+tc of a 16-lane group holds tile X[4tr+rr][4tc+cc] at
// x[rr*4+cc].  acc += A@B:
//   A-slice (tr,K): quad-mate K -> DPP quad_perm[K,K,K,K].
//   B-slice (K,tc): lane (K,tc) -> ds_swizzle BitMode src=(lane&0x13)|(K<<2).
template<int K>
__device__ __forceinline__ void mm_step(float acc[16], const float a[16], const float b[16]) {
  float bb[16];
#pragma unroll
  for (int e = 0; e < 16; ++e)
    bb[e] = __int_as_float(__builtin_amdgcn_ds_swizzle(__float_as_int(b[e]), (K << 7) | 0x13));
#pragma unroll
  for (int rr = 0; rr < 4; ++rr) {
    const float a0 = __int_as_float(__builtin_amdgcn_mov_dpp(__float_as_int(a[rr*4+0]), K*0x55, 0xF, 0xF, true));
    const float a1 = __int_as_float(__builtin_amdgcn_mov_dpp(__float_as_int(a[rr*4+1]), K*0x55, 0xF, 0xF, true));
    const float a2 = __int_as_float(__builtin_amdgcn_mov_dpp(__float_as_int(a[rr*4+2]), K*0x55, 0xF, 0xF, true));
    const float a3 = __int_as_float(__builtin_amdgcn_mov_dpp(__float_as_int(a[rr*4+3]), K*0x55, 0xF, 0xF, true));
#pragma unroll
    for (int cc = 0; cc < 4; ++cc)
      acc[rr*4+cc] = fmaf(a3, bb[12+cc], fmaf(a2, bb[8+cc], fmaf(a1, bb[4+cc], fmaf(a0, bb[cc], acc[rr*4+cc]))));
  }
}
__device__ __forceinline__ void mmreg(float acc[16], const float a[16], const float b[16]) {
  mm_step<0>(acc, a, b); mm_step<1>(acc, a, b);
  mm_step<2>(acc, a, b); mm_step<3>(acc, a, b);
}

// ---------------- k0: rho table + hoisted G-power basis ----------------
__global__ __launch_bounds__(256) void k0_prep(const float* __restrict__ A1,
                                               const float* __restrict__ A2,
                                               float* __restrict__ ws) {
  __shared__ float S[2][256], W2[4][256], W3[8][256], W4[16][256];
  const int tid = threadIdx.x;
  {
    int i_ = tid >> 4, j_ = tid & 15;
    S[0][tid] = A1[i_*16+j_] - A1[j_*16+i_];
    S[1][tid] = A2[i_*16+j_] - A2[j_*16+i_];
  }
  __syncthreads();
  const int i = tid >> 4, j = tid & 15;
#pragma unroll
  for (int p = 0; p < 4; ++p) {
    const float* a = S[p>>1]; const float* bm = S[p&1];
    float acc = 0.f;
    for (int k = 0; k < 16; ++k) acc = fmaf(a[i*16+k], bm[k*16+j], acc);
    W2[p][tid] = acc;
  }
  __syncthreads();
#pragma unroll
  for (int p = 0; p < 8; ++p) {
    const float* a = S[p>>2]; const float* bm = W2[p&3];
    float acc = 0.f;
    for (int k = 0; k < 16; ++k) acc = fmaf(a[i*16+k], bm[k*16+j], acc);
    W3[p][tid] = acc;
  }
  __syncthreads();
#pragma unroll
  for (int p = 0; p < 16; ++p) {
    const float* a = S[p>>3]; const float* bm = W3[p&7];
    float acc = 0.f;
    for (int k = 0; k < 16; ++k) acc = fmaf(a[i*16+k], bm[k*16+j], acc);
    W4[p][tid] = acc;
  }
  __syncthreads();
  float* M = ws + NA;
  M[ 0*256+tid] = S[0][tid];
  M[ 1*256+tid] = S[1][tid];
  M[ 2*256+tid] = W2[0][tid];
  M[ 3*256+tid] = W2[1][tid] + W2[2][tid];
  M[ 4*256+tid] = W2[3][tid];
  M[ 5*256+tid] = W3[0][tid];
  M[ 6*256+tid] = W3[1][tid] + W3[2][tid] + W3[4][tid];
  M[ 7*256+tid] = W3[3][tid] + W3[5][tid] + W3[6][tid];
  M[ 8*256+tid] = W3[7][tid];
  M[ 9*256+tid] = W4[0][tid];
  M[10*256+tid] = W4[1][tid] + W4[2][tid] + W4[4][tid] + W4[8][tid];
  M[11*256+tid] = W4[3][tid] + W4[5][tid] + W4[6][tid] + W4[9][tid] + W4[10][tid] + W4[12][tid];
  M[12*256+tid] = W4[7][tid] + W4[11][tid] + W4[13][tid] + W4[14][tid];
  M[13*256+tid] = W4[15][tid];
  if (tid < NA) {
    const float th = (float)tid * (PI_F / NA);
    const float c = cosf(th), s = sinf(th);
    float v[16];
    float n2 = 0.f;
#pragma unroll
    for (int jj = 0; jj < 16; ++jj) { v[jj] = sinf(1.7f*(float)(jj+1) + th) + 0.25f; n2 += v[jj]*v[jj]; }
    float inv = rsqrtf(n2);
#pragma unroll
    for (int jj = 0; jj < 16; ++jj) v[jj] *= inv;
    float lam = 0.f;
    for (int it = 0; it < 14; ++it) {
      float w[16];
#pragma unroll
      for (int ii = 0; ii < 16; ++ii) {
        float a1 = 0.f, a2 = 0.f;
#pragma unroll
        for (int jj = 0; jj < 16; ++jj) { a1 = fmaf(S[0][ii*16+jj], v[jj], a1); a2 = fmaf(S[1][ii*16+jj], v[jj], a2); }
        w[ii] = c*a1 + s*a2;
      }
      n2 = 0.f;
#pragma unroll
      for (int ii = 0; ii < 16; ++ii) n2 += w[ii]*w[ii];
      lam = sqrtf(n2);
      inv = (lam > 1e-20f) ? 1.f/lam : 0.f;
#pragma unroll
      for (int ii = 0; ii < 16; ++ii) v[ii] = w[ii]*inv;
    }
    ws[tid] = lam * 1.05f;
  }
}

// ---------------- k1: per-chunk scan, register-resident mms ----------------
// Qs padded: element (m, row i, col j) at m*QMS + (i>>2)*QTR + (i&3)*16 + j.
// Per-lane norm bound hoisted: 1 atan2/sqrt per chunk instead of 8.
__global__ __launch_bounds__(256, 2) void k1_chunk(const float* __restrict__ Z,
                                                   const float* __restrict__ wsrc,
                                                   float* __restrict__ Aout)
{
  __shared__ float Qs[NM*QMS];
  __shared__ float rhos[NA];
  const int tid = threadIdx.x;
  for (int e = tid; e < NM*256; e += 256) {
    const int m = e >> 8, i = (e >> 4) & 15, j = e & 15;
    Qs[m*QMS + (i>>2)*QTR + (i&3)*16 + j] = wsrc[NA + e];
  }
  if (tid < NA) rhos[tid] = wsrc[tid];
  __syncthreads();

  const int g  = tid >> 4;
  const int u  = tid & 15;
  const int tr = u >> 2;
  const int tc = u & 3;
  const int gw = (tid & 63) >> 4;
  const int qbase = tr*QTR + tc*4;

  const int cid    = blockIdx.x * GPB + g;
  const int b      = cid >> 9;          // / KC (KC=512)
  const int kchunk = cid & (KC-1);
  const int t0     = kchunk * CH;

  const float trtc = (tr == tc) ? 1.f : 0.f;
  const int tz = t0 + u;
  float2 za = *(const float2*)&Z[(size_t)(b*NT + (tz < NT ? tz : NT-1)) * 2];

  // per-lane spectral-norm bound for its own timestep (only u<CH lanes are
  // ever consumed via the shfl below)
  float nrm_own;
  {
    float r_ = sqrtf(za.x*za.x + za.y*za.y);
    float th = atan2f(za.y, za.x);
    if (th < 0.f) th += PI_F;
    int idx = ((int)(th * ((float)NA / PI_F) + 0.5f)) & (NA - 1);
    nrm_own = r_ * rhos[idx];
  }

  float lt[16];
#pragma unroll
  for (int rr = 0; rr < 4; ++rr)
#pragma unroll
    for (int cc = 0; cc < 4; ++cc) lt[rr*4+cc] = (rr == cc) ? trtc : 0.f;

  const int fstep = (kchunk == 0) ? 1 : 0;

  for (int tt = 0; tt < CH; ++tt) {
    const size_t obase = (size_t)(b*NT + t0 + tt) * 256 + (size_t)(tr*64) + 4*tc;

    const int src = (gw << 4) + tt;
    float z1 = __shfl(za.x, src);
    float z2 = __shfl(za.y, src);
    float nrm = __shfl(nrm_own, src);
    nrm = fmaxf(nrm, __shfl_xor(nrm, 16));
    nrm = fmaxf(nrm, __shfl_xor(nrm, 32));     // wave-uniform
    int s = 0;
    if (nrm > 1.0f) s = (int)ceilf(log2f(nrm));
    const float scl = exp2f(-(float)s);

    if (kchunk == 0 && tt == 0) {
#pragma unroll
      for (int rr = 0; rr < 4; ++rr)
        *(float4*)&Aout[obase + rr*16] =
          make_float4(lt[rr*4+0], lt[rr*4+1], lt[rr*4+2], lt[rr*4+3]);
      continue;
    }

    const float x = z1*scl, y = z2*scl;
    const float x2 = x*x, xy = x*y, y2 = y*y;
    const float x3 = x2*x, x2y = x2*y, xy2 = x*y2, y3 = y2*y;
    const float zc[NM] = { x, y, x2, xy, y2, x3, x2y, xy2, y3,
                           x2*x2, x3*y, x2*y2, x*y3, y2*y2 };
    const float WP[NM] = { 1.f,1.f, .5f,.5f,.5f, C3c,C3c,C3c,C3c, 0.f,0.f,0.f,0.f,0.f };
    const float WU[NM] = { C5c,C5c, C6c,C6c,C6c, C7c,C7c,C7c,C7c, C8c,C8c,C8c,C8c,C8c };

    float pp[16], uu[16], g4[16];
#pragma unroll
    for (int rr = 0; rr < 4; ++rr)
#pragma unroll
      for (int cc = 0; cc < 4; ++cc) {
        pp[rr*4+cc] = (rr == cc) ? trtc : 0.f;
        uu[rr*4+cc] = (rr == cc) ? trtc * C4c : 0.f;
        g4[rr*4+cc] = 0.f;
      }
#pragma unroll
    for (int m = 0; m < NM; ++m) {
      const float am = zc[m] * WP[m];
      const float bm = zc[m] * WU[m];
#pragma unroll
      for (int rr = 0; rr < 4; ++rr) {
        float4 v = *(const float4*)&Qs[m*QMS + rr*16 + qbase];
        if (m < 9) {
          pp[rr*4+0] = fmaf(am, v.x, pp[rr*4+0]);
          pp[rr*4+1] = fmaf(am, v.y, pp[rr*4+1]);
          pp[rr*4+2] = fmaf(am, v.z, pp[rr*4+2]);
          pp[rr*4+3] = fmaf(am, v.w, pp[rr*4+3]);
        } else {
          g4[rr*4+0] = fmaf(zc[m], v.x, g4[rr*4+0]);
          g4[rr*4+1] = fmaf(zc[m], v.y, g4[rr*4+1]);
          g4[rr*4+2] = fmaf(zc[m], v.z, g4[rr*4+2]);
          g4[rr*4+3] = fmaf(zc[m], v.w, g4[rr*4+3]);
        }
        uu[rr*4+0] = fmaf(bm, v.x, uu[rr*4+0]);
        uu[rr*4+1] = fmaf(bm, v.y, uu[rr*4+1]);
        uu[rr*4+2] = fmaf(bm, v.z, uu[rr*4+2]);
        uu[rr*4+3] = fmaf(bm, v.w, uu[rr*4+3]);
      }
    }

    mmreg(pp, g4, uu);                         // E = P1 + G4*U

    for (int q = 0; q < s; ++q) {
      float acc[16];
#pragma unroll
      for (int e = 0; e < 16; ++e) acc[e] = 0.f;
      mmreg(acc, pp, pp);
#pragma unroll
      for (int e = 0; e < 16; ++e) pp[e] = acc[e];
    }
    if (tt == fstep) {
#pragma unroll
      for (int e = 0; e < 16; ++e) lt[e] = pp[e];
    } else {
      float acc[16];
#pragma unroll
      for (int e = 0; e < 16; ++e) acc[e] = 0.f;
      mmreg(acc, lt, pp);
#pragma unroll
      for (int e = 0; e < 16; ++e) lt[e] = acc[e];
    }
#pragma unroll
    for (int rr = 0; rr < 4; ++rr)
      *(float4*)&Aout[obase + rr*16] =
        make_float4(lt[rr*4+0], lt[rr*4+1], lt[rr*4+2], lt[rr*4+3]);
  }
}

// ---------------- carry tree + fixup (round-10 proven versions) ----------------
// Stash in Binv (per batch): partial carries at t=k*8 (k=0..511),
// subgroup totals at t=128*sb+1, supercarries at t=128*sb+2 (sb=0..31).
#define ROWB 72
#define MATS (4*ROWB)
#define LGS (2*MATS + 8)
#define BX 0
#define BY MATS
#define WSYNC() asm volatile("s_waitcnt lgkmcnt(0)" ::: "memory")

#define MM_FMA(A_, B0_, B1_, B2_, B3_, base) \
  acc[base+0] = fmaf(A_.w, B3_.x, fmaf(A_.z, B2_.x, fmaf(A_.y, B1_.x, fmaf(A_.x, B0_.x, acc[base+0])))); \
  acc[base+1] = fmaf(A_.w, B3_.y, fmaf(A_.z, B2_.y, fmaf(A_.y, B1_.y, fmaf(A_.x, B0_.y, acc[base+1])))); \
  acc[base+2] = fmaf(A_.w, B3_.z, fmaf(A_.z, B2_.z, fmaf(A_.y, B1_.z, fmaf(A_.x, B0_.z, acc[base+2])))); \
  acc[base+3] = fmaf(A_.w, B3_.w, fmaf(A_.z, B2_.w, fmaf(A_.y, B1_.w, fmaf(A_.x, B0_.w, acc[base+3]))));

template<bool CLR>
__device__ __forceinline__ void mmg(float acc[16], const float* sb, int offA, int offB,
                                    const int xA[4], const int xB[4], int trR) {
  if (CLR) {
#pragma unroll
    for (int e = 0; e < 16; ++e) acc[e] = 0.f;
  }
#pragma unroll
  for (int kk = 0; kk < 4; ++kk) {
    const float* pa = sb + offA + trR + xA[kk];
    const float* pb = sb + offB + kk*ROWB + xB[kk];
    float4 a0 = *(const float4*)(pa +  0);
    float4 a1 = *(const float4*)(pa + 16);
    float4 a2 = *(const float4*)(pa + 32);
    float4 a3 = *(const float4*)(pa + 48);
    float4 b0 = *(const float4*)(pb +  0);
    float4 b1 = *(const float4*)(pb + 16);
    float4 b2 = *(const float4*)(pb + 32);
    float4 b3 = *(const float4*)(pb + 48);
    MM_FMA(a0, b0, b1, b2, b3, 0)
    MM_FMA(a1, b0, b1, b2, b3, 4)
    MM_FMA(a2, b0, b1, b2, b3, 8)
    MM_FMA(a3, b0, b1, b2, b3, 12)
  }
}

__device__ __forceinline__ void st4(float* sb, int offD, const float v[16], int trR, int xD) {
  float* p = sb + offD + trR + xD;
#pragma unroll
  for (int rr = 0; rr < 4; ++rr)
    *(float4*)(p + rr*16) = make_float4(v[rr*4+0], v[rr*4+1], v[rr*4+2], v[rr*4+3]);
}

__global__ __launch_bounds__(256) void k2a(const float* __restrict__ Aout,
                                           float* __restrict__ Binv) {
  __shared__ float Cy[256], Lt[256];
  const int tid = threadIdx.x, i = tid >> 4, j = tid & 15;
  const int b = blockIdx.x >> 5, sb = blockIdx.x & 31;
  Cy[tid] = (i == j) ? 1.f : 0.f;
  float nxt = Aout[((size_t)(b*NT + (sb*16)*CH + CH - 1))*256 + tid];
  __syncthreads();
  for (int q = 0; q < 16; ++q) {
    const int k = sb*16 + q;
    Binv[((size_t)(b*NT + k*CH))*256 + tid] = Cy[tid];
    Lt[tid] = nxt;
    __syncthreads();
    if (q < 15) nxt = Aout[((size_t)(b*NT + (k+1)*CH + CH - 1))*256 + tid];
    float a2 = 0.f;
#pragma unroll
    for (int m = 0; m < 16; ++m) a2 = fmaf(Cy[i*16+m], Lt[m*16+j], a2);
    __syncthreads();
    Cy[tid] = a2;
    __syncthreads();
  }
  Binv[((size_t)(b*NT + sb*128 + 1))*256 + tid] = Cy[tid];
}

__global__ __launch_bounds__(256) void k2b(float* __restrict__ Binv) {
  __shared__ float Cy[256], Lt[256];
  const int tid = threadIdx.x, i = tid >> 4, j = tid & 15;
  const int b = blockIdx.x;
  Cy[tid] = (i == j) ? 1.f : 0.f;
  float nxt = Binv[((size_t)(b*NT + 1))*256 + tid];
  __syncthreads();
  for (int sb2 = 0; sb2 < 32; ++sb2) {
    Binv[((size_t)(b*NT + sb2*128 + 2))*256 + tid] = Cy[tid];
    Lt[tid] = nxt;
    __syncthreads();
    if (sb2 < 31) nxt = Binv[((size_t)(b*NT + (sb2+1)*128 + 1))*256 + tid];
    float a2 = 0.f;
#pragma unroll
    for (int m = 0; m < 16; ++m) a2 = fmaf(Cy[i*16+m], Lt[m*16+j], a2);
    __syncthreads();
    Cy[tid] = a2;
    __syncthreads();
  }
}

__global__ __launch_bounds__(256, 2) void k3_apply(float* __restrict__ Aout,
                                                   float* __restrict__ Binv)
{
  __shared__ __align__(16) float lds[GPB * LGS];
  __shared__ float SupL[256];
  const int tid = threadIdx.x;
  const int g   = tid >> 4;
  const int u   = tid & 15;
  const int tr  = u >> 2;
  const int tc  = u & 3;
  const int trR = tr * ROWB;
  float* sb_ = lds + g * LGS;
  const int xA[4] = { ((0^tr)<<2), ((1^tr)<<2), ((2^tr)<<2), ((3^tr)<<2) };
  const int xB[4] = { ((tc^0)<<2), ((tc^1)<<2), ((tc^2)<<2), ((tc^3)<<2) };
  const int xD    = ((tc^tr)<<2);

  const int b   = blockIdx.x >> 5;
  const int sbq = blockIdx.x & 31;
  const int k   = sbq*16 + g;
  const int t0  = k * CH;

  SupL[tid] = Binv[((size_t)(b*NT + sbq*128 + 2))*256 + tid];
  {
    const float* srcp = &Binv[((size_t)(b*NT + k*CH))*256];
#pragma unroll
    for (int rr = 0; rr < 4; ++rr) {
      float4 v = *(const float4*)&srcp[rr*64 + 4*u];
      *(float4*)&sb_[BX + rr*ROWB + tr*16 + ((tc^rr)<<2)] = v;
    }
  }
  __syncthreads();

  float wt[16];
  {
    float* acc = wt;
#pragma unroll
    for (int e = 0; e < 16; ++e) acc[e] = 0.f;
#pragma unroll
    for (int kk = 0; kk < 4; ++kk) {
      const float* pb = sb_ + BX + kk*ROWB + xB[kk];
      float4 b0 = *(const float4*)(pb +  0);
      float4 b1 = *(const float4*)(pb + 16);
      float4 b2 = *(const float4*)(pb + 32);
      float4 b3 = *(const float4*)(pb + 48);
      float4 a0 = *(const float4*)&SupL[(4*tr+0)*16 + 4*kk];
      float4 a1 = *(const float4*)&SupL[(4*tr+1)*16 + 4*kk];
      float4 a2 = *(const float4*)&SupL[(4*tr+2)*16 + 4*kk];
      float4 a3 = *(const float4*)&SupL[(4*tr+3)*16 + 4*kk];
      MM_FMA(a0, b0, b1, b2, b3, 0)
      MM_FMA(a1, b0, b1, b2, b3, 4)
      MM_FMA(a2, b0, b1, b2, b3, 8)
      MM_FMA(a3, b0, b1, b2, b3, 12)
    }
  }
  st4(sb_, BY, wt, trR, xD);
  WSYNC();

  float acc[16];
  for (int tt = 0; tt < CH; ++tt) {
    const size_t base = ((size_t)(b*NT + t0 + tt))*256;
#pragma unroll
    for (int rr = 0; rr < 4; ++rr) {
      float4 v = *(const float4*)&Aout[base + rr*64 + 4*u];
      *(float4*)&sb_[BX + rr*ROWB + tr*16 + ((tc^rr)<<2)] = v;
    }
    WSYNC();
    mmg<true>(acc, sb_, BY, BX, xA, xB, trR);
    const size_t obase = base + (size_t)(tr*64) + 4*tc;
#pragma unroll
    for (int rr = 0; rr < 4; ++rr)
      *(float4*)&Aout[obase + rr*16] =
        make_float4(acc[rr*4+0], acc[rr*4+1], acc[rr*4+2], acc[rr*4+3]);
    st4(sb_, BX, acc, trR, xD); WSYNC();
    const float* pt = sb_ + BX + tc*ROWB + ((tr^tc)<<2);
    float4 f0 = *(const float4*)(pt +  0);
    float4 f1 = *(const float4*)(pt + 16);
    float4 f2 = *(const float4*)(pt + 32);
    float4 f3 = *(const float4*)(pt + 48);
    *(float4*)&Binv[obase +  0] = make_float4(f0.x, f1.x, f2.x, f3.x);
    *(float4*)&Binv[obase + 16] = make_float4(f0.y, f1.y, f2.y, f3.y);
    *(float4*)&Binv[obase + 32] = make_float4(f0.z, f1.z, f2.z, f3.z);
    *(float4*)&Binv[obase + 48] = make_float4(f0.w, f1.w, f2.w, f3.w);
    WSYNC();
  }
}

extern "C" void kernel_launch(void* const* d_in, const int* in_sizes, int n_in,
                              void* d_out, int out_size, void* d_ws, size_t ws_size,
                              hipStream_t stream) {
  const float* Z  = (const float*)d_in[0];
  const float* A1 = (const float*)d_in[1];
  const float* A2 = (const float*)d_in[2];
  float* ws   = (float*)d_ws;
  float* Aout = (float*)d_out;
  float* Binv = Aout + (size_t)NB * NT * 256;

  k0_prep<<<1, 256, 0, stream>>>(A1, A2, ws);
  k1_chunk<<<NB * KC / GPB, 256, 0, stream>>>(Z, ws, Aout);
  k2a<<<NB * 32, 256, 0, stream>>>(Aout, Binv);
  k2b<<<NB, 256, 0, stream>>>(Binv);
  k3_apply<<<NB * 32, 256, 0, stream>>>(Aout, Binv);
}

// Round 14
// 523.219 us; speedup vs baseline: 1.0242x; 1.0066x over previous
//
#include <hip/hip_runtime.h>

#define NB 64
#define NT 4096
#define CH 8
#define KC (NT/CH)        // 512 chunks per batch
#define GPB 16            // 16-lane groups per 256-thread block
#define NA 128            // spectral-norm table size over [0, pi)
#define NM 14             // hoisted G-power basis matrices
#define QTR 72            // padded tr-block stride (72 mod 32 = 8 -> 2-way max)
#define QMS (4*QTR)       // 288 floats per padded Q matrix
#define PI_F 3.14159265358979f
#define THETA 1.35f       // Taylor-8 scaling radius; err/step = 1.35^9/9! = 4.1e-5

#define C3c (1.f/6.f)
#define C4c (1.f/24.f)
#define C5c (1.f/120.f)
#define C6c (1.f/720.f)
#define C7c (1.f/5040.f)
#define C8c (1.f/40320.f)

// ---------------- register-resident 16x16 matmul (k1 only) ----------------
template<int K>
__device__ __forceinline__ void mm_step(float acc[16], const float a[16], const float b[16]) {
  float bb[16];
#pragma unroll
  for (int e = 0; e < 16; ++e)
    bb[e] = __int_as_float(__builtin_amdgcn_ds_swizzle(__float_as_int(b[e]), (K << 7) | 0x13));
#pragma unroll
  for (int rr = 0; rr < 4; ++rr) {
    const float a0 = __int_as_float(__builtin_amdgcn_mov_dpp(__float_as_int(a[rr*4+0]), K*0x55, 0xF, 0xF, true));
    const float a1 = __int_as_float(__builtin_amdgcn_mov_dpp(__float_as_int(a[rr*4+1]), K*0x55, 0xF, 0xF, true));
    const float a2 = __int_as_float(__builtin_amdgcn_mov_dpp(__float_as_int(a[rr*4+2]), K*0x55, 0xF, 0xF, true));
    const float a3 = __int_as_float(__builtin_amdgcn_mov_dpp(__float_as_int(a[rr*4+3]), K*0x55, 0xF, 0xF, true));
#pragma unroll
    for (int cc = 0; cc < 4; ++cc)
      acc[rr*4+cc] = fmaf(a3, bb[12+cc], fmaf(a2, bb[8+cc], fmaf(a1, bb[4+cc], fmaf(a0, bb[cc], acc[rr*4+cc]))));
  }
}
__device__ __forceinline__ void mmreg(float acc[16], const float a[16], const float b[16]) {
  mm_step<0>(acc, a, b); mm_step<1>(acc, a, b);
  mm_step<2>(acc, a, b); mm_step<3>(acc, a, b);
}

// ---------------- k0: rho table + hoisted G-power basis ----------------
__global__ __launch_bounds__(256) void k0_prep(const float* __restrict__ A1,
                                               const float* __restrict__ A2,
                                               float* __restrict__ ws) {
  __shared__ float S[2][256], W2[4][256], W3[8][256], W4[16][256];
  const int tid = threadIdx.x;
  {
    int i_ = tid >> 4, j_ = tid & 15;
    S[0][tid] = A1[i_*16+j_] - A1[j_*16+i_];
    S[1][tid] = A2[i_*16+j_] - A2[j_*16+i_];
  }
  __syncthreads();
  const int i = tid >> 4, j = tid & 15;
#pragma unroll
  for (int p = 0; p < 4; ++p) {
    const float* a = S[p>>1]; const float* bm = S[p&1];
    float acc = 0.f;
    for (int k = 0; k < 16; ++k) acc = fmaf(a[i*16+k], bm[k*16+j], acc);
    W2[p][tid] = acc;
  }
  __syncthreads();
#pragma unroll
  for (int p = 0; p < 8; ++p) {
    const float* a = S[p>>2]; const float* bm = W2[p&3];
    float acc = 0.f;
    for (int k = 0; k < 16; ++k) acc = fmaf(a[i*16+k], bm[k*16+j], acc);
    W3[p][tid] = acc;
  }
  __syncthreads();
#pragma unroll
  for (int p = 0; p < 16; ++p) {
    const float* a = S[p>>3]; const float* bm = W3[p&7];
    float acc = 0.f;
    for (int k = 0; k < 16; ++k) acc = fmaf(a[i*16+k], bm[k*16+j], acc);
    W4[p][tid] = acc;
  }
  __syncthreads();
  float* M = ws + NA;
  M[ 0*256+tid] = S[0][tid];
  M[ 1*256+tid] = S[1][tid];
  M[ 2*256+tid] = W2[0][tid];
  M[ 3*256+tid] = W2[1][tid] + W2[2][tid];
  M[ 4*256+tid] = W2[3][tid];
  M[ 5*256+tid] = W3[0][tid];
  M[ 6*256+tid] = W3[1][tid] + W3[2][tid] + W3[4][tid];
  M[ 7*256+tid] = W3[3][tid] + W3[5][tid] + W3[6][tid];
  M[ 8*256+tid] = W3[7][tid];
  M[ 9*256+tid] = W4[0][tid];
  M[10*256+tid] = W4[1][tid] + W4[2][tid] + W4[4][tid] + W4[8][tid];
  M[11*256+tid] = W4[3][tid] + W4[5][tid] + W4[6][tid] + W4[9][tid] + W4[10][tid] + W4[12][tid];
  M[12*256+tid] = W4[7][tid] + W4[11][tid] + W4[13][tid] + W4[14][tid];
  M[13*256+tid] = W4[15][tid];
  if (tid < NA) {
    const float th = (float)tid * (PI_F / NA);
    const float c = cosf(th), s = sinf(th);
    float v[16];
    float n2 = 0.f;
#pragma unroll
    for (int jj = 0; jj < 16; ++jj) { v[jj] = sinf(1.7f*(float)(jj+1) + th) + 0.25f; n2 += v[jj]*v[jj]; }
    float inv = rsqrtf(n2);
#pragma unroll
    for (int jj = 0; jj < 16; ++jj) v[jj] *= inv;
    float lam = 0.f;
    for (int it = 0; it < 14; ++it) {
      float w[16];
#pragma unroll
      for (int ii = 0; ii < 16; ++ii) {
        float a1 = 0.f, a2 = 0.f;
#pragma unroll
        for (int jj = 0; jj < 16; ++jj) { a1 = fmaf(S[0][ii*16+jj], v[jj], a1); a2 = fmaf(S[1][ii*16+jj], v[jj], a2); }
        w[ii] = c*a1 + s*a2;
      }
      n2 = 0.f;
#pragma unroll
      for (int ii = 0; ii < 16; ++ii) n2 += w[ii]*w[ii];
      lam = sqrtf(n2);
      inv = (lam > 1e-20f) ? 1.f/lam : 0.f;
#pragma unroll
      for (int ii = 0; ii < 16; ++ii) v[ii] = w[ii]*inv;
    }
    ws[tid] = lam * 1.05f;
  }
}

// ---------------- k1: per-chunk scan, register-resident mms ----------------
__global__ __launch_bounds__(256, 2) void k1_chunk(const float* __restrict__ Z,
                                                   const float* __restrict__ wsrc,
                                                   float* __restrict__ Aout)
{
  __shared__ float Qs[NM*QMS];
  __shared__ float rhos[NA];
  const int tid = threadIdx.x;
  for (int e = tid; e < NM*256; e += 256) {
    const int m = e >> 8, i = (e >> 4) & 15, j = e & 15;
    Qs[m*QMS + (i>>2)*QTR + (i&3)*16 + j] = wsrc[NA + e];
  }
  if (tid < NA) rhos[tid] = wsrc[tid];
  __syncthreads();

  const int g  = tid >> 4;
  const int u  = tid & 15;
  const int tr = u >> 2;
  const int tc = u & 3;
  const int gw = (tid & 63) >> 4;
  const int qbase = tr*QTR + tc*4;

  const int cid    = blockIdx.x * GPB + g;
  const int b      = cid >> 9;          // / KC (KC=512)
  const int kchunk = cid & (KC-1);
  const int t0     = kchunk * CH;

  const float trtc = (tr == tc) ? 1.f : 0.f;
  const int tz = t0 + u;
  float2 za = *(const float2*)&Z[(size_t)(b*NT + (tz < NT ? tz : NT-1)) * 2];

  float nrm_own;
  {
    float r_ = sqrtf(za.x*za.x + za.y*za.y);
    float th = atan2f(za.y, za.x);
    if (th < 0.f) th += PI_F;
    int idx = ((int)(th * ((float)NA / PI_F) + 0.5f)) & (NA - 1);
    nrm_own = r_ * rhos[idx];
  }

  float lt[16];
#pragma unroll
  for (int rr = 0; rr < 4; ++rr)
#pragma unroll
    for (int cc = 0; cc < 4; ++cc) lt[rr*4+cc] = (rr == cc) ? trtc : 0.f;

  const int fstep = (kchunk == 0) ? 1 : 0;

  for (int tt = 0; tt < CH; ++tt) {
    const size_t obase = (size_t)(b*NT + t0 + tt) * 256 + (size_t)(tr*64) + 4*tc;

    const int src = (gw << 4) + tt;
    float z1 = __shfl(za.x, src);
    float z2 = __shfl(za.y, src);
    float nrm = __shfl(nrm_own, src);
    nrm = fmaxf(nrm, __shfl_xor(nrm, 16));
    nrm = fmaxf(nrm, __shfl_xor(nrm, 32));     // wave-uniform
    int s = 0;
    if (nrm > THETA) s = (int)ceilf(log2f(nrm * (1.f/THETA)));
    const float scl = exp2f(-(float)s);

    if (kchunk == 0 && tt == 0) {
#pragma unroll
      for (int rr = 0; rr < 4; ++rr)
        *(float4*)&Aout[obase + rr*16] =
          make_float4(lt[rr*4+0], lt[rr*4+1], lt[rr*4+2], lt[rr*4+3]);
      continue;
    }

    const float x = z1*scl, y = z2*scl;
    const float x2 = x*x, xy = x*y, y2 = y*y;
    const float x3 = x2*x, x2y = x2*y, xy2 = x*y2, y3 = y2*y;
    const float zc[NM] = { x, y, x2, xy, y2, x3, x2y, xy2, y3,
                           x2*x2, x3*y, x2*y2, x*y3, y2*y2 };
    const float WP[NM] = { 1.f,1.f, .5f,.5f,.5f, C3c,C3c,C3c,C3c, 0.f,0.f,0.f,0.f,0.f };
    const float WU[NM] = { C5c,C5c, C6c,C6c,C6c, C7c,C7c,C7c,C7c, C8c,C8c,C8c,C8c,C8c };

    float pp[16], uu[16], g4[16];
#pragma unroll
    for (int rr = 0; rr < 4; ++rr)
#pragma unroll
      for (int cc = 0; cc < 4; ++cc) {
        pp[rr*4+cc] = (rr == cc) ? trtc : 0.f;
        uu[rr*4+cc] = (rr == cc) ? trtc * C4c : 0.f;
        g4[rr*4+cc] = 0.f;
      }
#pragma unroll
    for (int m = 0; m < NM; ++m) {
      const float am = zc[m] * WP[m];
      const float bm = zc[m] * WU[m];
#pragma unroll
      for (int rr = 0; rr < 4; ++rr) {
        float4 v = *(const float4*)&Qs[m*QMS + rr*16 + qbase];
        if (m < 9) {
          pp[rr*4+0] = fmaf(am, v.x, pp[rr*4+0]);
          pp[rr*4+1] = fmaf(am, v.y, pp[rr*4+1]);
          pp[rr*4+2] = fmaf(am, v.z, pp[rr*4+2]);
          pp[rr*4+3] = fmaf(am, v.w, pp[rr*4+3]);
        } else {
          g4[rr*4+0] = fmaf(zc[m], v.x, g4[rr*4+0]);
          g4[rr*4+1] = fmaf(zc[m], v.y, g4[rr*4+1]);
          g4[rr*4+2] = fmaf(zc[m], v.z, g4[rr*4+2]);
          g4[rr*4+3] = fmaf(zc[m], v.w, g4[rr*4+3]);
        }
        uu[rr*4+0] = fmaf(bm, v.x, uu[rr*4+0]);
        uu[rr*4+1] = fmaf(bm, v.y, uu[rr*4+1]);
        uu[rr*4+2] = fmaf(bm, v.z, uu[rr*4+2]);
        uu[rr*4+3] = fmaf(bm, v.w, uu[rr*4+3]);
      }
    }

    mmreg(pp, g4, uu);                         // E = P1 + G4*U

    for (int q = 0; q < s; ++q) {
      float acc[16];
#pragma unroll
      for (int e = 0; e < 16; ++e) acc[e] = 0.f;
      mmreg(acc, pp, pp);
#pragma unroll
      for (int e = 0; e < 16; ++e) pp[e] = acc[e];
    }
    if (tt == fstep) {
#pragma unroll
      for (int e = 0; e < 16; ++e) lt[e] = pp[e];
    } else {
      float acc[16];
#pragma unroll
      for (int e = 0; e < 16; ++e) acc[e] = 0.f;
      mmreg(acc, lt, pp);
#pragma unroll
      for (int e = 0; e < 16; ++e) lt[e] = acc[e];
    }
#pragma unroll
    for (int rr = 0; rr < 4; ++rr)
      *(float4*)&Aout[obase + rr*16] =
        make_float4(lt[rr*4+0], lt[rr*4+1], lt[rr*4+2], lt[rr*4+3]);
  }
}

// ---------------- carry tree + fixup ----------------
// Stash in Binv (per batch): partial carries at t=k*8 (k=0..511),
// subgroup totals at t=128*sb+1, supercarries at t=128*sb+2 (sb=0..31).
#define ROWB 72
#define MATS (4*ROWB)
#define LGS (2*MATS + 8)
#define BX 0
#define BY MATS
#define WSYNC() asm volatile("s_waitcnt lgkmcnt(0)" ::: "memory")

#define MM_FMA(A_, B0_, B1_, B2_, B3_, base) \
  acc[base+0] = fmaf(A_.w, B3_.x, fmaf(A_.z, B2_.x, fmaf(A_.y, B1_.x, fmaf(A_.x, B0_.x, acc[base+0])))); \
  acc[base+1] = fmaf(A_.w, B3_.y, fmaf(A_.z, B2_.y, fmaf(A_.y, B1_.y, fmaf(A_.x, B0_.y, acc[base+1])))); \
  acc[base+2] = fmaf(A_.w, B3_.z, fmaf(A_.z, B2_.z, fmaf(A_.y, B1_.z, fmaf(A_.x, B0_.z, acc[base+2])))); \
  acc[base+3] = fmaf(A_.w, B3_.w, fmaf(A_.z, B2_.w, fmaf(A_.y, B1_.w, fmaf(A_.x, B0_.w, acc[base+3]))));

template<bool CLR>
__device__ __forceinline__ void mmg(float acc[16], const float* sb, int offA, int offB,
                                    const int xA[4], const int xB[4], int trR) {
  if (CLR) {
#pragma unroll
    for (int e = 0; e < 16; ++e) acc[e] = 0.f;
  }
#pragma unroll
  for (int kk = 0; kk < 4; ++kk) {
    const float* pa = sb + offA + trR + xA[kk];
    const float* pb = sb + offB + kk*ROWB + xB[kk];
    float4 a0 = *(const float4*)(pa +  0);
    float4 a1 = *(const float4*)(pa + 16);
    float4 a2 = *(const float4*)(pa + 32);
    float4 a3 = *(const float4*)(pa + 48);
    float4 b0 = *(const float4*)(pb +  0);
    float4 b1 = *(const float4*)(pb + 16);
    float4 b2 = *(const float4*)(pb + 32);
    float4 b3 = *(const float4*)(pb + 48);
    MM_FMA(a0, b0, b1, b2, b3, 0)
    MM_FMA(a1, b0, b1, b2, b3, 4)
    MM_FMA(a2, b0, b1, b2, b3, 8)
    MM_FMA(a3, b0, b1, b2, b3, 12)
  }
}

__device__ __forceinline__ void st4(float* sb, int offD, const float v[16], int trR, int xD) {
  float* p = sb + offD + trR + xD;
#pragma unroll
  for (int rr = 0; rr < 4; ++rr)
    *(float4*)(p + rr*16) = make_float4(v[rr*4+0], v[rr*4+1], v[rr*4+2], v[rr*4+3]);
}

__global__ __launch_bounds__(256) void k2a(const float* __restrict__ Aout,
                                           float* __restrict__ Binv) {
  __shared__ float Cy[256], Lt[256];
  const int tid = threadIdx.x, i = tid >> 4, j = tid & 15;
  const int b = blockIdx.x >> 5, sb = blockIdx.x & 31;
  Cy[tid] = (i == j) ? 1.f : 0.f;
  float nxt = Aout[((size_t)(b*NT + (sb*16)*CH + CH - 1))*256 + tid];
  __syncthreads();
  for (int q = 0; q < 16; ++q) {
    const int k = sb*16 + q;
    Binv[((size_t)(b*NT + k*CH))*256 + tid] = Cy[tid];
    Lt[tid] = nxt;
    __syncthreads();
    if (q < 15) nxt = Aout[((size_t)(b*NT + (k+1)*CH + CH - 1))*256 + tid];
    float a2 = 0.f;
#pragma unroll
    for (int m = 0; m < 16; ++m) a2 = fmaf(Cy[i*16+m], Lt[m*16+j], a2);
    __syncthreads();
    Cy[tid] = a2;
    __syncthreads();
  }
  Binv[((size_t)(b*NT + sb*128 + 1))*256 + tid] = Cy[tid];
}

__global__ __launch_bounds__(256) void k2b(float* __restrict__ Binv) {
  __shared__ float Cy[256], Lt[256];
  const int tid = threadIdx.x, i = tid >> 4, j = tid & 15;
  const int b = blockIdx.x;
  Cy[tid] = (i == j) ? 1.f : 0.f;
  float nxt = Binv[((size_t)(b*NT + 1))*256 + tid];
  __syncthreads();
  for (int sb2 = 0; sb2 < 32; ++sb2) {
    Binv[((size_t)(b*NT + sb2*128 + 2))*256 + tid] = Cy[tid];
    Lt[tid] = nxt;
    __syncthreads();
    if (sb2 < 31) nxt = Binv[((size_t)(b*NT + (sb2+1)*128 + 1))*256 + tid];
    float a2 = 0.f;
#pragma unroll
    for (int m = 0; m < 16; ++m) a2 = fmaf(Cy[i*16+m], Lt[m*16+j], a2);
    __syncthreads();
    Cy[tid] = a2;
    __syncthreads();
  }
}

// k3: staged-LDS mm (proven) + ds_bpermute in-register transpose (proven
// correct in round 11) -> one LDS round-trip per tile instead of two.
__global__ __launch_bounds__(256, 2) void k3_apply(float* __restrict__ Aout,
                                                   float* __restrict__ Binv)
{
  __shared__ __align__(16) float lds[GPB * LGS];
  __shared__ float SupL[256];
  const int tid = threadIdx.x;
  const int g   = tid >> 4;
  const int u   = tid & 15;
  const int tr  = u >> 2;
  const int tc  = u & 3;
  const int gw  = (tid & 63) >> 4;
  const int trR = tr * ROWB;
  float* sb_ = lds + g * LGS;
  const int xA[4] = { ((0^tr)<<2), ((1^tr)<<2), ((2^tr)<<2), ((3^tr)<<2) };
  const int xB[4] = { ((tc^0)<<2), ((tc^1)<<2), ((tc^2)<<2), ((tc^3)<<2) };
  const int xD    = ((tc^tr)<<2);

  const int b   = blockIdx.x >> 5;
  const int sbq = blockIdx.x & 31;
  const int k   = sbq*16 + g;
  const int t0  = k * CH;

  SupL[tid] = Binv[((size_t)(b*NT + sbq*128 + 2))*256 + tid];
  {
    const float* srcp = &Binv[((size_t)(b*NT + k*CH))*256];
#pragma unroll
    for (int rr = 0; rr < 4; ++rr) {
      float4 v = *(const float4*)&srcp[rr*64 + 4*u];
      *(float4*)&sb_[BX + rr*ROWB + tr*16 + ((tc^rr)<<2)] = v;
    }
  }
  __syncthreads();

  float wt[16];
  {
    float* acc = wt;
#pragma unroll
    for (int e = 0; e < 16; ++e) acc[e] = 0.f;
#pragma unroll
    for (int kk = 0; kk < 4; ++kk) {
      const float* pb = sb_ + BX + kk*ROWB + xB[kk];
      float4 b0 = *(const float4*)(pb +  0);
      float4 b1 = *(const float4*)(pb + 16);
      float4 b2 = *(const float4*)(pb + 32);
      float4 b3 = *(const float4*)(pb + 48);
      float4 a0 = *(const float4*)&SupL[(4*tr+0)*16 + 4*kk];
      float4 a1 = *(const float4*)&SupL[(4*tr+1)*16 + 4*kk];
      float4 a2 = *(const float4*)&SupL[(4*tr+2)*16 + 4*kk];
      float4 a3 = *(const float4*)&SupL[(4*tr+3)*16 + 4*kk];
      MM_FMA(a0, b0, b1, b2, b3, 0)
      MM_FMA(a1, b0, b1, b2, b3, 4)
      MM_FMA(a2, b0, b1, b2, b3, 8)
      MM_FMA(a3, b0, b1, b2, b3, 12)
    }
  }
  st4(sb_, BY, wt, trR, xD);   // BY := W for the whole loop
  WSYNC();

  const int bidx = ((gw << 4) + tc*4 + tr) * 4;   // transpose mate (wave-local)
  float acc[16], tp[16];
  for (int tt = 0; tt < CH; ++tt) {
    const size_t base = ((size_t)(b*NT + t0 + tt))*256;
#pragma unroll
    for (int rr = 0; rr < 4; ++rr) {
      float4 v = *(const float4*)&Aout[base + rr*64 + 4*u];
      *(float4*)&sb_[BX + rr*ROWB + tr*16 + ((tc^rr)<<2)] = v;
    }
    WSYNC();
    mmg<true>(acc, sb_, BY, BX, xA, xB, trR);         // A = W @ L
    const size_t obase = base + (size_t)(tr*64) + 4*tc;
#pragma unroll
    for (int rr = 0; rr < 4; ++rr)
      *(float4*)&Aout[obase + rr*16] =
        make_float4(acc[rr*4+0], acc[rr*4+1], acc[rr*4+2], acc[rr*4+3]);
#pragma unroll
    for (int e = 0; e < 16; ++e)
      tp[e] = __int_as_float(__builtin_amdgcn_ds_bpermute(bidx, __float_as_int(acc[e])));
#pragma unroll
    for (int rr = 0; rr < 4; ++rr)
      *(float4*)&Binv[obase + rr*16] =
        make_float4(tp[rr], tp[4+rr], tp[8+rr], tp[12+rr]);   // A^T tile
    WSYNC();   // drain ds ops before next iteration overwrites BX
  }
}

extern "C" void kernel_launch(void* const* d_in, const int* in_sizes, int n_in,
                              void* d_out, int out_size, void* d_ws, size_t ws_size,
                              hipStream_t stream) {
  const float* Z  = (const float*)d_in[0];
  const float* A1 = (const float*)d_in[1];
  const float* A2 = (const float*)d_in[2];
  float* ws   = (float*)d_ws;
  float* Aout = (float*)d_out;
  float* Binv = Aout + (size_t)NB * NT * 256;

  k0_prep<<<1, 256, 0, stream>>>(A1, A2, ws);
  k1_chunk<<<NB * KC / GPB, 256, 0, stream>>>(Z, ws, Aout);
  k2a<<<NB * 32, 256, 0, stream>>>(Aout, Binv);
  k2b<<<NB, 256, 0, stream>>>(Binv);
  k3_apply<<<NB * 32, 256, 0, stream>>>(Aout, Binv);
}